// Round 1
// baseline (1433.454 us; speedup 1.0000x reference)
//
#include <hip/hip_runtime.h>
#include <hip/hip_bf16.h>
#include <math.h>

#define B_  2
#define D_  8
#define H_  56
#define W_  56
#define C_  256
#define NH_ 8
#define HD_ 32
#define N_  98
#define NWIN_TOT 512
#define TOK (B_*D_*H_*W_)   // 50176
#define HID 1024

// window row -> token index (shift+partition on read == reverse+unshift on write)
__device__ __forceinline__ int tok_of_winrow(int r) {
    int wid  = r / N_;
    int n    = r - wid * N_;
    int b    = wid >> 8;          // /256 windows per batch
    int rem  = wid & 255;
    int di   = rem >> 6;          // 4 windows along D
    int hi   = (rem >> 3) & 7;    // 8 along H
    int wi   = rem & 7;           // 8 along W
    int wd   = n / 49;
    int rem2 = n - wd * 49;
    int wh   = rem2 / 7;
    int ww   = rem2 - wh * 7;
    int d = di * 2 + wd + 1; if (d >= D_) d -= D_;
    int h = hi * 7 + wh + 3; if (h >= H_) h -= H_;
    int w = wi * 7 + ww + 3; if (w >= W_) w -= W_;
    return ((b * D_ + d) * H_ + h) * W_ + w;
}

// ---------------- LayerNorm (1 wave per row, C=256 -> float4/lane) ----------
template<bool GATHER>
__global__ __launch_bounds__(256)
void ln_kernel(const float* __restrict__ x, const float* __restrict__ g,
               const float* __restrict__ bta, float* __restrict__ out, int nrows) {
    int wave = blockIdx.x * 4 + (threadIdx.x >> 6);
    int lane = threadIdx.x & 63;
    if (wave >= nrows) return;
    int srow = GATHER ? tok_of_winrow(wave) : wave;
    float4 v = ((const float4*)(x + (size_t)srow * C_))[lane];
    float s  = v.x + v.y + v.z + v.w;
    float ss = v.x*v.x + v.y*v.y + v.z*v.z + v.w*v.w;
    #pragma unroll
    for (int o = 32; o; o >>= 1) { s += __shfl_xor(s, o); ss += __shfl_xor(ss, o); }
    float mean = s * (1.0f / C_);
    float var  = ss * (1.0f / C_) - mean * mean;
    float rstd = rsqrtf(var + 1e-5f);
    float4 gg = ((const float4*)g)[lane];
    float4 bb = ((const float4*)bta)[lane];
    float4 o4;
    o4.x = (v.x - mean) * rstd * gg.x + bb.x;
    o4.y = (v.y - mean) * rstd * gg.y + bb.y;
    o4.z = (v.z - mean) * rstd * gg.z + bb.z;
    o4.w = (v.w - mean) * rstd * gg.w + bb.w;
    ((float4*)(out + (size_t)wave * C_))[lane] = o4;
}

// ---------------- rel-pos bias gather: bias[h][i][j] ------------------------
__global__ void bias_kernel(const int* __restrict__ rel_idx,
                            const float* __restrict__ rpb,
                            float* __restrict__ biasbuf) {
    int idx = blockIdx.x * blockDim.x + threadIdx.x;
    if (idx >= NH_ * N_ * N_) return;
    int h  = idx / (N_ * N_);
    int ij = idx - h * (N_ * N_);
    biasbuf[idx] = rpb[rel_idx[ij] * NH_ + h];
}

// ---------------- fp32 tile GEMM, C[r,o] = dot(A[r,:], W[o,:]) + b[o] -------
// MODE 0: plain store   MODE 1: proj scatter + residual(x)
// MODE 2: exact GELU    MODE 3: fc2 + residual (in-place on Cout)
#define BM 64
#define BN 64
#define BKK 32

__device__ __forceinline__ float gelu_exact(float x) {
    return 0.5f * x * (1.0f + erff(x * 0.70710678118654752f));
}

template<int MODE>
__global__ __launch_bounds__(256)
void gemm_nt(const float* __restrict__ A, const float* __restrict__ Wm,
             const float* __restrict__ bias, float* __restrict__ Cout,
             const float* __restrict__ resid, int M, int K, int Nout) {
    __shared__ __align__(16) float As[BKK * BM];
    __shared__ __align__(16) float Ws[BKK * BN];
    int tid = threadIdx.x;
    int tx = tid & 15, ty = tid >> 4;
    int m0 = blockIdx.x * BM;
    int n0 = blockIdx.y * BN;
    float acc[4][4] = {{0.f}};

    for (int k0 = 0; k0 < K; k0 += BKK) {
        #pragma unroll
        for (int u = 0; u < 2; ++u) {
            int fid = tid * 2 + u;            // 0..511
            int row = fid >> 3, c4 = fid & 7;
            float4 a = *(const float4*)(A  + (size_t)(m0 + row) * K + k0 + c4 * 4);
            float4 w = *(const float4*)(Wm + (size_t)(n0 + row) * K + k0 + c4 * 4);
            As[(c4 * 4 + 0) * BM + row] = a.x;
            As[(c4 * 4 + 1) * BM + row] = a.y;
            As[(c4 * 4 + 2) * BM + row] = a.z;
            As[(c4 * 4 + 3) * BM + row] = a.w;
            Ws[(c4 * 4 + 0) * BN + row] = w.x;
            Ws[(c4 * 4 + 1) * BN + row] = w.y;
            Ws[(c4 * 4 + 2) * BN + row] = w.z;
            Ws[(c4 * 4 + 3) * BN + row] = w.w;
        }
        __syncthreads();
        #pragma unroll
        for (int kk = 0; kk < BKK; ++kk) {
            float4 a4 = *(const float4*)&As[kk * BM + ty * 4];
            float4 w4 = *(const float4*)&Ws[kk * BN + tx * 4];
            float av[4] = {a4.x, a4.y, a4.z, a4.w};
            float wv[4] = {w4.x, w4.y, w4.z, w4.w};
            #pragma unroll
            for (int i = 0; i < 4; ++i)
                #pragma unroll
                for (int j = 0; j < 4; ++j)
                    acc[i][j] += av[i] * wv[j];
        }
        __syncthreads();
    }

    float4 b4 = *(const float4*)(bias + n0 + tx * 4);
    #pragma unroll
    for (int i = 0; i < 4; ++i) {
        int gr = m0 + ty * 4 + i;
        float4 v;
        v.x = acc[i][0] + b4.x;
        v.y = acc[i][1] + b4.y;
        v.z = acc[i][2] + b4.z;
        v.w = acc[i][3] + b4.w;
        if (MODE == 0) {
            *(float4*)(Cout + (size_t)gr * Nout + n0 + tx * 4) = v;
        } else if (MODE == 1) {
            int tok = tok_of_winrow(gr);
            float4 r4 = *(const float4*)(resid + (size_t)tok * C_ + n0 + tx * 4);
            v.x += r4.x; v.y += r4.y; v.z += r4.z; v.w += r4.w;
            *(float4*)(Cout + (size_t)tok * C_ + n0 + tx * 4) = v;
        } else if (MODE == 2) {
            v.x = gelu_exact(v.x); v.y = gelu_exact(v.y);
            v.z = gelu_exact(v.z); v.w = gelu_exact(v.w);
            *(float4*)(Cout + (size_t)gr * Nout + n0 + tx * 4) = v;
        } else {
            float4 r4 = *(const float4*)(resid + (size_t)gr * Nout + n0 + tx * 4);
            v.x += r4.x; v.y += r4.y; v.z += r4.z; v.w += r4.w;
            *(float4*)(Cout + (size_t)gr * Nout + n0 + tx * 4) = v;
        }
    }
}

// ---------------- attention: one block per (window, head), flash-style ------
__global__ __launch_bounds__(128)
void attn_kernel(const float* __restrict__ qkv, const float* __restrict__ biasbuf,
                 const float* __restrict__ mask, float* __restrict__ attn_out) {
    __shared__ __align__(16) float Ks[N_ * HD_];
    __shared__ __align__(16) float Vs[N_ * HD_];
    int wid = blockIdx.x >> 3;
    int hh  = blockIdx.x & 7;
    int tid = threadIdx.x;
    const size_t rowbase = (size_t)wid * N_ * 768;

    for (int idx = tid; idx < N_ * HD_ / 4; idx += 128) {  // 784 float4s each
        int j = idx >> 3, c4 = idx & 7;
        const float* kp = qkv + rowbase + (size_t)j * 768 + 256 + hh * 32 + c4 * 4;
        ((float4*)Ks)[idx] = *(const float4*)kp;
        ((float4*)Vs)[idx] = *(const float4*)(kp + 256);
    }
    __syncthreads();

    int i = tid;
    if (i < N_) {
        const float scale = 0.17677669529663687f;  // 1/sqrt(32)
        float q[32];
        const float* qp = qkv + rowbase + (size_t)i * 768 + hh * 32;
        #pragma unroll
        for (int c4 = 0; c4 < 8; ++c4) {
            float4 t = *(const float4*)(qp + c4 * 4);
            q[c4*4+0] = t.x * scale; q[c4*4+1] = t.y * scale;
            q[c4*4+2] = t.z * scale; q[c4*4+3] = t.w * scale;
        }
        const float* mrow = mask + (size_t)(wid & 255) * (N_ * N_) + i * N_;
        const float* brow = biasbuf + (size_t)hh * (N_ * N_) + i * N_;
        const float4* Ks4 = (const float4*)Ks;
        float m = -INFINITY, l = 0.f;
        float o[32];
        #pragma unroll
        for (int c = 0; c < 32; ++c) o[c] = 0.f;

        for (int j = 0; j < N_; ++j) {
            float s = 0.f;
            #pragma unroll
            for (int t = 0; t < 8; ++t) {
                float4 kv = Ks4[j * 8 + t];
                s += q[t*4+0]*kv.x + q[t*4+1]*kv.y + q[t*4+2]*kv.z + q[t*4+3]*kv.w;
            }
            s += mrow[j] + brow[j];
            if (s > m) {
                float corr = __expf(m - s);      // expf(-inf)=0 on first iter
                l = l * corr + 1.f;
                #pragma unroll
                for (int c = 0; c < 32; ++c) o[c] = o[c] * corr + Vs[j * 32 + c];
                m = s;
            } else {
                float p = __expf(s - m);
                l += p;
                #pragma unroll
                for (int c = 0; c < 32; ++c) o[c] += p * Vs[j * 32 + c];
            }
        }
        float rinv = 1.f / l;
        float* op = attn_out + ((size_t)(wid * N_ + i)) * C_ + hh * 32;
        #pragma unroll
        for (int c4 = 0; c4 < 8; ++c4) {
            float4 t;
            t.x = o[c4*4+0] * rinv; t.y = o[c4*4+1] * rinv;
            t.z = o[c4*4+2] * rinv; t.w = o[c4*4+3] * rinv;
            *(float4*)(op + c4 * 4) = t;
        }
    }
}

// ---------------------------------------------------------------------------
extern "C" void kernel_launch(void* const* d_in, const int* in_sizes, int n_in,
                              void* d_out, int out_size, void* d_ws, size_t ws_size,
                              hipStream_t stream) {
    const float* x      = (const float*)d_in[0];
    const float* qkv_w  = (const float*)d_in[1];
    const float* qkv_b  = (const float*)d_in[2];
    const float* proj_w = (const float*)d_in[3];
    const float* proj_b = (const float*)d_in[4];
    const float* rpb    = (const float*)d_in[5];
    const float* ln1_g  = (const float*)d_in[6];
    const float* ln1_b  = (const float*)d_in[7];
    const float* ln2_g  = (const float*)d_in[8];
    const float* ln2_b  = (const float*)d_in[9];
    const float* fc1_w  = (const float*)d_in[10];
    const float* fc1_b  = (const float*)d_in[11];
    const float* fc2_w  = (const float*)d_in[12];
    const float* fc2_b  = (const float*)d_in[13];
    const int*   rel_idx= (const int*)d_in[14];
    const float* mask   = (const float*)d_in[15];
    float* out = (float*)d_out;

    char* ws = (char*)d_ws;
    float* regionA = (float*)ws;                                   // qkv(154MB) / hidden(205MB)
    float* regionB = (float*)(ws + (size_t)TOK * HID * 4);         // win / attn_out / h2 (51MB)
    float* biasbuf = (float*)(ws + (size_t)TOK * HID * 4 + (size_t)TOK * C_ * 4);

    // K0: rel-pos bias gather (8 x 98 x 98)
    bias_kernel<<<(NH_ * N_ * N_ + 255) / 256, 256, 0, stream>>>(rel_idx, rpb, biasbuf);

    // K1: LN1 + cyclic shift + window partition -> regionB (win, 50176 x 256)
    ln_kernel<true><<<TOK / 4, 256, 0, stream>>>(x, ln1_g, ln1_b, regionB, TOK);

    // K2: QKV GEMM -> regionA (50176 x 768)
    {
        dim3 g(TOK / BM, 768 / BN);
        gemm_nt<0><<<g, 256, 0, stream>>>(regionB, qkv_w, qkv_b, regionA, nullptr, TOK, 256, 768);
    }

    // K3: windowed attention -> regionB (attn_out, 50176 x 256)
    attn_kernel<<<NWIN_TOT * NH_, 128, 0, stream>>>(regionA, biasbuf, mask, regionB);

    // K4: proj GEMM + window reverse + unshift + residual(x) -> out (= x1)
    {
        dim3 g(TOK / BM, 256 / BN);
        gemm_nt<1><<<g, 256, 0, stream>>>(regionB, proj_w, proj_b, out, x, TOK, 256, 256);
    }

    // K5: LN2 -> regionB (h2)
    ln_kernel<false><<<TOK / 4, 256, 0, stream>>>(out, ln2_g, ln2_b, regionB, TOK);

    // K6: fc1 + exact GELU -> regionA (hidden, 50176 x 1024)
    {
        dim3 g(TOK / BM, HID / BN);
        gemm_nt<2><<<g, 256, 0, stream>>>(regionB, fc1_w, fc1_b, regionA, nullptr, TOK, 256, HID);
    }

    // K7: fc2 + residual (in-place on out)
    {
        dim3 g(TOK / BM, 256 / BN);
        gemm_nt<3><<<g, 256, 0, stream>>>(regionA, fc2_w, fc2_b, out, out, TOK, HID, 256);
    }
}

// Round 2
// 528.627 us; speedup vs baseline: 2.7117x; 2.7117x over previous
//
#include <hip/hip_runtime.h>
#include <hip/hip_bf16.h>
#include <math.h>

#define B_  2
#define D_  8
#define H_  56
#define W_  56
#define C_  256
#define NH_ 8
#define HD_ 32
#define N_  98
#define NWIN_TOT 512
#define TOK (B_*D_*H_*W_)   // 50176
#define HID 1024

typedef short bf16x8 __attribute__((ext_vector_type(8)));
typedef float f32x4  __attribute__((ext_vector_type(4)));

__device__ __forceinline__ ushort f2b(float f) {
    union { float f; unsigned u; } v; v.f = f;
    unsigned r = v.u + 0x7fff + ((v.u >> 16) & 1);
    return (ushort)(r >> 16);
}
__device__ __forceinline__ float b2f(ushort h) {
    union { unsigned u; float f; } v; v.u = ((unsigned)h) << 16;
    return v.f;
}
__device__ __forceinline__ unsigned pack2(float lo, float hi) {
    return (unsigned)f2b(lo) | ((unsigned)f2b(hi) << 16);
}

__device__ __forceinline__ void glds16(const void* gsrc, void* lds_dst) {
    __builtin_amdgcn_global_load_lds(
        (const __attribute__((address_space(1))) unsigned int*)gsrc,
        (__attribute__((address_space(3))) unsigned int*)lds_dst,
        16, 0, 0);
}

// window row -> token index (shift+partition on read == reverse+unshift on write)
__device__ __forceinline__ int tok_of_winrow(int r) {
    int wid  = r / N_;
    int n    = r - wid * N_;
    int b    = wid >> 8;
    int rem  = wid & 255;
    int di   = rem >> 6;
    int hi   = (rem >> 3) & 7;
    int wi   = rem & 7;
    int wd   = n / 49;
    int rem2 = n - wd * 49;
    int wh   = rem2 / 7;
    int ww   = rem2 - wh * 7;
    int d = di * 2 + wd + 1; if (d >= D_) d -= D_;
    int h = hi * 7 + wh + 3; if (h >= H_) h -= H_;
    int w = wi * 7 + ww + 3; if (w >= W_) w -= W_;
    return ((b * D_ + d) * H_ + h) * W_ + w;
}

__device__ __forceinline__ float gelu_exact(float x) {
    return 0.5f * x * (1.0f + erff(x * 0.70710678118654752f));
}

// ---------------- LayerNorm (1 wave/row) -> bf16 out ------------------------
template<bool GATHER>
__global__ __launch_bounds__(256)
void ln_kernel(const float* __restrict__ x, const float* __restrict__ g,
               const float* __restrict__ bta, ushort* __restrict__ out, int nrows) {
    int wave = blockIdx.x * 4 + (threadIdx.x >> 6);
    int lane = threadIdx.x & 63;
    if (wave >= nrows) return;
    int srow = GATHER ? tok_of_winrow(wave) : wave;
    float4 v = ((const float4*)(x + (size_t)srow * C_))[lane];
    float s  = v.x + v.y + v.z + v.w;
    float ss = v.x*v.x + v.y*v.y + v.z*v.z + v.w*v.w;
    #pragma unroll
    for (int o = 32; o; o >>= 1) { s += __shfl_xor(s, o); ss += __shfl_xor(ss, o); }
    float mean = s * (1.0f / C_);
    float var  = ss * (1.0f / C_) - mean * mean;
    float rstd = rsqrtf(var + 1e-5f);
    float4 gg = ((const float4*)g)[lane];
    float4 bb = ((const float4*)bta)[lane];
    ushort4 o4;
    o4.x = f2b((v.x - mean) * rstd * gg.x + bb.x);
    o4.y = f2b((v.y - mean) * rstd * gg.y + bb.y);
    o4.z = f2b((v.z - mean) * rstd * gg.z + bb.z);
    o4.w = f2b((v.w - mean) * rstd * gg.w + bb.w);
    ((ushort4*)(out + (size_t)wave * C_))[lane] = o4;
}

// ---------------- rel-pos bias gather ---------------------------------------
__global__ void bias_kernel(const int* __restrict__ rel_idx,
                            const float* __restrict__ rpb,
                            float* __restrict__ biasbuf) {
    int idx = blockIdx.x * blockDim.x + threadIdx.x;
    if (idx >= NH_ * N_ * N_) return;
    int h  = idx / (N_ * N_);
    int ij = idx - h * (N_ * N_);
    biasbuf[idx] = rpb[rel_idx[ij] * NH_ + h];
}

// ---------------- fp32 -> bf16 weight convert -------------------------------
__global__ void f2b_kernel(const float* __restrict__ src, ushort* __restrict__ dst, int n) {
    int i = (blockIdx.x * blockDim.x + threadIdx.x) * 4;
    if (i >= n) return;
    float4 v = *(const float4*)(src + i);
    ushort4 o; o.x = f2b(v.x); o.y = f2b(v.y); o.z = f2b(v.z); o.w = f2b(v.w);
    *(ushort4*)(dst + i) = o;
}

// ---------------- bf16 MFMA GEMM: C[r,o] = A[r,:] . W[o,:] + b[o] -----------
// A: M x K bf16 row-major; Wm: N x K bf16 row-major (B^T layout).
// 128x128 tile, BK=64, 4 waves (2x2), 64x64 per wave, 16x16x32 MFMA.
// LDS: linear [row][8 chunks of 16B], source pre-swizzled chunk = c ^ (row&7).
// MODE 0: bf16 store (+bias)   MODE 1: proj scatter + residual -> fp32 out
// MODE 2: GELU -> bf16         MODE 3: fc2 + residual -> fp32 (in place)
template<int MODE>
__global__ __launch_bounds__(256)
void gemm_bf16(const ushort* __restrict__ A, const ushort* __restrict__ Wm,
               const float* __restrict__ bias, void* __restrict__ Cout,
               const void* __restrict__ resid, int M, int K, int Nout) {
    __shared__ __align__(16) char lds[32768];
    char* ldsA = lds;
    char* ldsB = lds + 16384;
    const int tid  = threadIdx.x;
    const int wv   = tid >> 6, lane = tid & 63;
    const int m0   = blockIdx.x * 128, n0 = blockIdx.y * 128;
    const int wrow = (wv >> 1) * 64, wcol = (wv & 1) * 64;
    const int lr8  = lane >> 3, lc = lane & 7;

    f32x4 acc[4][4] = {};

    const ushort* Ag[4]; const ushort* Bg[4];
    #pragma unroll
    for (int i = 0; i < 4; ++i) {
        int row = (wv * 4 + i) * 8 + lr8;          // 0..127
        int gc  = lc ^ (row & 7);                  // pre-swizzled source chunk
        Ag[i] = A  + (size_t)(m0 + row) * K + gc * 8;
        Bg[i] = Wm + (size_t)(n0 + row) * K + gc * 8;
    }

    for (int k0 = 0; k0 < K; k0 += 64) {
        #pragma unroll
        for (int i = 0; i < 4; ++i) {
            glds16(Ag[i] + k0, ldsA + (wv * 4 + i) * 1024);
            glds16(Bg[i] + k0, ldsB + (wv * 4 + i) * 1024);
        }
        __syncthreads();
        #pragma unroll
        for (int kk = 0; kk < 2; ++kk) {
            bf16x8 af[4], bfr[4];
            #pragma unroll
            for (int i = 0; i < 4; ++i) {
                int r = wrow + i * 16 + (lane & 15);
                int c = (lane >> 4) + kk * 4;
                af[i]  = *(const bf16x8*)(ldsA + r * 128 + ((c ^ (r & 7)) * 16));
                int r2 = wcol + i * 16 + (lane & 15);
                bfr[i] = *(const bf16x8*)(ldsB + r2 * 128 + ((c ^ (r2 & 7)) * 16));
            }
            #pragma unroll
            for (int i = 0; i < 4; ++i)
                #pragma unroll
                for (int j = 0; j < 4; ++j)
                    acc[i][j] = __builtin_amdgcn_mfma_f32_16x16x32_bf16(af[i], bfr[j], acc[i][j], 0, 0, 0);
        }
        __syncthreads();
    }

    // epilogue: C row = m0+wrow+i*16+(lane>>4)*4+r, col = n0+wcol+j*16+(lane&15)
    int colg[4]; float bv[4];
    #pragma unroll
    for (int j = 0; j < 4; ++j) {
        colg[j] = n0 + wcol + j * 16 + (lane & 15);
        bv[j]   = bias[colg[j]];
    }
    #pragma unroll
    for (int i = 0; i < 4; ++i) {
        #pragma unroll
        for (int r = 0; r < 4; ++r) {
            int rowg = m0 + wrow + i * 16 + ((lane >> 4) << 2) + r;
            int tok = (MODE == 1) ? tok_of_winrow(rowg) : rowg;
            #pragma unroll
            for (int j = 0; j < 4; ++j) {
                float v = acc[i][j][r] + bv[j];
                if (MODE == 0) {
                    ((ushort*)Cout)[(size_t)rowg * Nout + colg[j]] = f2b(v);
                } else if (MODE == 1) {
                    v += ((const float*)resid)[(size_t)tok * C_ + colg[j]];
                    ((float*)Cout)[(size_t)tok * C_ + colg[j]] = v;
                } else if (MODE == 2) {
                    ((ushort*)Cout)[(size_t)rowg * Nout + colg[j]] = f2b(gelu_exact(v));
                } else {
                    v += ((const float*)resid)[(size_t)rowg * Nout + colg[j]];
                    ((float*)Cout)[(size_t)rowg * Nout + colg[j]] = v;
                }
            }
        }
    }
}

// ---------------- attention: one block per (window, head), flash-style ------
__global__ __launch_bounds__(128)
void attn_kernel(const ushort* __restrict__ qkv, const float* __restrict__ biasbuf,
                 const float* __restrict__ mask, ushort* __restrict__ attn_out) {
    __shared__ __align__(16) float Ks[N_ * HD_];
    __shared__ __align__(16) float Vs[N_ * HD_];
    int wid = blockIdx.x >> 3;
    int hh  = blockIdx.x & 7;
    int tid = threadIdx.x;
    const size_t rowbase = (size_t)wid * N_ * 768;

    for (int idx = tid; idx < N_ * 4; idx += 128) {   // 392 chunks of 8 bf16
        int j = idx >> 2, c8 = idx & 3;
        const ushort* kp = qkv + rowbase + (size_t)j * 768 + 256 + hh * 32 + c8 * 8;
        uint4 kv = *(const uint4*)kp;
        uint4 vv = *(const uint4*)(kp + 256);
        float* kd = Ks + j * 32 + c8 * 8;
        float* vd = Vs + j * 32 + c8 * 8;
        kd[0] = b2f((ushort)(kv.x & 0xffff)); kd[1] = b2f((ushort)(kv.x >> 16));
        kd[2] = b2f((ushort)(kv.y & 0xffff)); kd[3] = b2f((ushort)(kv.y >> 16));
        kd[4] = b2f((ushort)(kv.z & 0xffff)); kd[5] = b2f((ushort)(kv.z >> 16));
        kd[6] = b2f((ushort)(kv.w & 0xffff)); kd[7] = b2f((ushort)(kv.w >> 16));
        vd[0] = b2f((ushort)(vv.x & 0xffff)); vd[1] = b2f((ushort)(vv.x >> 16));
        vd[2] = b2f((ushort)(vv.y & 0xffff)); vd[3] = b2f((ushort)(vv.y >> 16));
        vd[4] = b2f((ushort)(vv.z & 0xffff)); vd[5] = b2f((ushort)(vv.z >> 16));
        vd[6] = b2f((ushort)(vv.w & 0xffff)); vd[7] = b2f((ushort)(vv.w >> 16));
    }
    __syncthreads();

    int i = tid;
    if (i < N_) {
        const float scale = 0.17677669529663687f;  // 1/sqrt(32)
        float q[32];
        const ushort* qp = qkv + rowbase + (size_t)i * 768 + hh * 32;
        #pragma unroll
        for (int c8 = 0; c8 < 4; ++c8) {
            uint4 t = *(const uint4*)(qp + c8 * 8);
            float* qd = q + c8 * 8;
            qd[0] = b2f((ushort)(t.x & 0xffff)) * scale; qd[1] = b2f((ushort)(t.x >> 16)) * scale;
            qd[2] = b2f((ushort)(t.y & 0xffff)) * scale; qd[3] = b2f((ushort)(t.y >> 16)) * scale;
            qd[4] = b2f((ushort)(t.z & 0xffff)) * scale; qd[5] = b2f((ushort)(t.z >> 16)) * scale;
            qd[6] = b2f((ushort)(t.w & 0xffff)) * scale; qd[7] = b2f((ushort)(t.w >> 16)) * scale;
        }
        const float* mrow = mask + (size_t)(wid & 255) * (N_ * N_) + i * N_;
        const float* brow = biasbuf + (size_t)hh * (N_ * N_) + i * N_;
        const float4* Ks4 = (const float4*)Ks;
        float m = -INFINITY, l = 0.f;
        float o[32];
        #pragma unroll
        for (int c = 0; c < 32; ++c) o[c] = 0.f;

        for (int j = 0; j < N_; ++j) {
            float s = 0.f;
            #pragma unroll
            for (int t = 0; t < 8; ++t) {
                float4 kv = Ks4[j * 8 + t];
                s += q[t*4+0]*kv.x + q[t*4+1]*kv.y + q[t*4+2]*kv.z + q[t*4+3]*kv.w;
            }
            s += mrow[j] + brow[j];
            if (s > m) {
                float corr = __expf(m - s);
                l = l * corr + 1.f;
                #pragma unroll
                for (int c = 0; c < 32; ++c) o[c] = o[c] * corr + Vs[j * 32 + c];
                m = s;
            } else {
                float p = __expf(s - m);
                l += p;
                #pragma unroll
                for (int c = 0; c < 32; ++c) o[c] += p * Vs[j * 32 + c];
            }
        }
        float rinv = 1.f / l;
        ushort* op = attn_out + ((size_t)(wid * N_ + i)) * C_ + hh * 32;
        #pragma unroll
        for (int c8 = 0; c8 < 4; ++c8) {
            uint4 t;
            t.x = pack2(o[c8*8+0]*rinv, o[c8*8+1]*rinv);
            t.y = pack2(o[c8*8+2]*rinv, o[c8*8+3]*rinv);
            t.z = pack2(o[c8*8+4]*rinv, o[c8*8+5]*rinv);
            t.w = pack2(o[c8*8+6]*rinv, o[c8*8+7]*rinv);
            *(uint4*)(op + c8 * 8) = t;
        }
    }
}

// ---------------------------------------------------------------------------
extern "C" void kernel_launch(void* const* d_in, const int* in_sizes, int n_in,
                              void* d_out, int out_size, void* d_ws, size_t ws_size,
                              hipStream_t stream) {
    const float* x      = (const float*)d_in[0];
    const float* qkv_w  = (const float*)d_in[1];
    const float* qkv_b  = (const float*)d_in[2];
    const float* proj_w = (const float*)d_in[3];
    const float* proj_b = (const float*)d_in[4];
    const float* rpb    = (const float*)d_in[5];
    const float* ln1_g  = (const float*)d_in[6];
    const float* ln1_b  = (const float*)d_in[7];
    const float* ln2_g  = (const float*)d_in[8];
    const float* ln2_b  = (const float*)d_in[9];
    const float* fc1_w  = (const float*)d_in[10];
    const float* fc1_b  = (const float*)d_in[11];
    const float* fc2_w  = (const float*)d_in[12];
    const float* fc2_b  = (const float*)d_in[13];
    const int*   rel_idx= (const int*)d_in[14];
    const float* mask   = (const float*)d_in[15];
    float* out = (float*)d_out;

    char* ws = (char*)d_ws;
    ushort* regionA = (ushort*)ws;                                   // qkv(77MB)/hidden(103MB) bf16
    ushort* regionB = (ushort*)(ws + (size_t)TOK * HID * 2);         // win/attn_out/h2 bf16 (26MB)
    ushort* wq  = (ushort*)(ws + (size_t)TOK * HID * 2 + (size_t)TOK * C_ * 2);
    ushort* wp  = wq + 768 * 256;
    ushort* w1  = wp + 256 * 256;
    ushort* w2  = w1 + HID * 256;
    float* biasbuf = (float*)(w2 + 256 * HID);

    // K0: rel-pos bias gather + weight converts
    bias_kernel<<<(NH_ * N_ * N_ + 255) / 256, 256, 0, stream>>>(rel_idx, rpb, biasbuf);
    f2b_kernel<<<(768 * 256 / 4 + 255) / 256, 256, 0, stream>>>(qkv_w, wq, 768 * 256);
    f2b_kernel<<<(256 * 256 / 4 + 255) / 256, 256, 0, stream>>>(proj_w, wp, 256 * 256);
    f2b_kernel<<<(HID * 256 / 4 + 255) / 256, 256, 0, stream>>>(fc1_w, w1, HID * 256);
    f2b_kernel<<<(256 * HID / 4 + 255) / 256, 256, 0, stream>>>(fc2_w, w2, 256 * HID);

    // K1: LN1 + shift + window partition -> regionB bf16
    ln_kernel<true><<<TOK / 4, 256, 0, stream>>>(x, ln1_g, ln1_b, regionB, TOK);

    // K2: QKV GEMM -> regionA bf16 (50176 x 768)
    {
        dim3 g(TOK / 128, 768 / 128);
        gemm_bf16<0><<<g, 256, 0, stream>>>(regionB, wq, qkv_b, regionA, nullptr, TOK, 256, 768);
    }

    // K3: windowed attention -> regionB bf16
    attn_kernel<<<NWIN_TOT * NH_, 128, 0, stream>>>(regionA, biasbuf, mask, regionB);

    // K4: proj GEMM + window reverse + unshift + residual(x) -> out fp32
    {
        dim3 g(TOK / 128, 256 / 128);
        gemm_bf16<1><<<g, 256, 0, stream>>>(regionB, wp, proj_b, out, x, TOK, 256, 256);
    }

    // K5: LN2 -> regionB bf16
    ln_kernel<false><<<TOK / 4, 256, 0, stream>>>(out, ln2_g, ln2_b, regionB, TOK);

    // K6: fc1 + GELU -> regionA bf16 (50176 x 1024)
    {
        dim3 g(TOK / 128, HID / 128);
        gemm_bf16<2><<<g, 256, 0, stream>>>(regionB, w1, fc1_b, regionA, nullptr, TOK, 256, HID);
    }

    // K7: fc2 + residual (in place on out)
    {
        dim3 g(TOK / 128, 256 / 128);
        gemm_bf16<3><<<g, 256, 0, stream>>>(regionA, w2, fc2_b, out, out, TOK, HID, 256);
    }
}

// Round 3
// 360.163 us; speedup vs baseline: 3.9800x; 1.4677x over previous
//
#include <hip/hip_runtime.h>
#include <hip/hip_bf16.h>
#include <math.h>

#define B_  2
#define D_  8
#define H_  56
#define W_  56
#define C_  256
#define NH_ 8
#define HD_ 32
#define N_  98
#define NWIN_TOT 512
#define TOK (B_*D_*H_*W_)   // 50176
#define HID 1024

typedef short bf16x8 __attribute__((ext_vector_type(8)));
typedef float f32x4  __attribute__((ext_vector_type(4)));

__device__ __forceinline__ ushort f2b(float f) {
    union { float f; unsigned u; } v; v.f = f;
    unsigned r = v.u + 0x7fff + ((v.u >> 16) & 1);
    return (ushort)(r >> 16);
}
__device__ __forceinline__ float b2f(ushort h) {
    union { unsigned u; float f; } v; v.u = ((unsigned)h) << 16;
    return v.f;
}

__device__ __forceinline__ void glds16(const void* gsrc, void* lds_dst) {
    __builtin_amdgcn_global_load_lds(
        (const __attribute__((address_space(1))) unsigned int*)gsrc,
        (__attribute__((address_space(3))) unsigned int*)lds_dst,
        16, 0, 0);
}

// window row -> token index (shift+partition on read == reverse+unshift on write)
__device__ __forceinline__ int tok_of_winrow(int r) {
    int wid  = r / N_;
    int n    = r - wid * N_;
    int b    = wid >> 8;
    int rem  = wid & 255;
    int di   = rem >> 6;
    int hi   = (rem >> 3) & 7;
    int wi   = rem & 7;
    int wd   = n / 49;
    int rem2 = n - wd * 49;
    int wh   = rem2 / 7;
    int ww   = rem2 - wh * 7;
    int d = di * 2 + wd + 1; if (d >= D_) d -= D_;
    int h = hi * 7 + wh + 3; if (h >= H_) h -= H_;
    int w = wi * 7 + ww + 3; if (w >= W_) w -= W_;
    return ((b * D_ + d) * H_ + h) * W_ + w;
}

__device__ __forceinline__ float gelu_exact(float x) {
    return 0.5f * x * (1.0f + erff(x * 0.70710678118654752f));
}

// ---------------- LayerNorm (1 wave/row) -> bf16 out ------------------------
template<bool GATHER>
__global__ __launch_bounds__(256)
void ln_kernel(const float* __restrict__ x, const float* __restrict__ g,
               const float* __restrict__ bta, ushort* __restrict__ out, int nrows) {
    int wave = blockIdx.x * 4 + (threadIdx.x >> 6);
    int lane = threadIdx.x & 63;
    if (wave >= nrows) return;
    int srow = GATHER ? tok_of_winrow(wave) : wave;
    float4 v = ((const float4*)(x + (size_t)srow * C_))[lane];
    float s  = v.x + v.y + v.z + v.w;
    float ss = v.x*v.x + v.y*v.y + v.z*v.z + v.w*v.w;
    #pragma unroll
    for (int o = 32; o; o >>= 1) { s += __shfl_xor(s, o); ss += __shfl_xor(ss, o); }
    float mean = s * (1.0f / C_);
    float var  = ss * (1.0f / C_) - mean * mean;
    float rstd = rsqrtf(var + 1e-5f);
    float4 gg = ((const float4*)g)[lane];
    float4 bb = ((const float4*)bta)[lane];
    ushort4 o4;
    o4.x = f2b((v.x - mean) * rstd * gg.x + bb.x);
    o4.y = f2b((v.y - mean) * rstd * gg.y + bb.y);
    o4.z = f2b((v.z - mean) * rstd * gg.z + bb.z);
    o4.w = f2b((v.w - mean) * rstd * gg.w + bb.w);
    ((ushort4*)(out + (size_t)wave * C_))[lane] = o4;
}

// ---------------- rel-pos bias gather ---------------------------------------
__global__ void bias_kernel(const int* __restrict__ rel_idx,
                            const float* __restrict__ rpb,
                            float* __restrict__ biasbuf) {
    int idx = blockIdx.x * blockDim.x + threadIdx.x;
    if (idx >= NH_ * N_ * N_) return;
    int h  = idx / (N_ * N_);
    int ij = idx - h * (N_ * N_);
    biasbuf[idx] = rpb[rel_idx[ij] * NH_ + h];
}

// ---------------- fp32 -> bf16 weight convert -------------------------------
__global__ void f2b_kernel(const float* __restrict__ src, ushort* __restrict__ dst, int n) {
    int i = (blockIdx.x * blockDim.x + threadIdx.x) * 4;
    if (i >= n) return;
    float4 v = *(const float4*)(src + i);
    ushort4 o; o.x = f2b(v.x); o.y = f2b(v.y); o.z = f2b(v.z); o.w = f2b(v.w);
    *(ushort4*)(dst + i) = o;
}

// ---------------- bf16 MFMA GEMM (unchanged from round 2) -------------------
template<int MODE>
__global__ __launch_bounds__(256)
void gemm_bf16(const ushort* __restrict__ A, const ushort* __restrict__ Wm,
               const float* __restrict__ bias, void* __restrict__ Cout,
               const void* __restrict__ resid, int M, int K, int Nout) {
    __shared__ __align__(16) char lds[32768];
    char* ldsA = lds;
    char* ldsB = lds + 16384;
    const int tid  = threadIdx.x;
    const int wv   = tid >> 6, lane = tid & 63;
    const int m0   = blockIdx.x * 128, n0 = blockIdx.y * 128;
    const int wrow = (wv >> 1) * 64, wcol = (wv & 1) * 64;
    const int lr8  = lane >> 3, lc = lane & 7;

    f32x4 acc[4][4] = {};

    const ushort* Ag[4]; const ushort* Bg[4];
    #pragma unroll
    for (int i = 0; i < 4; ++i) {
        int row = (wv * 4 + i) * 8 + lr8;
        int gc  = lc ^ (row & 7);
        Ag[i] = A  + (size_t)(m0 + row) * K + gc * 8;
        Bg[i] = Wm + (size_t)(n0 + row) * K + gc * 8;
    }

    for (int k0 = 0; k0 < K; k0 += 64) {
        #pragma unroll
        for (int i = 0; i < 4; ++i) {
            glds16(Ag[i] + k0, ldsA + (wv * 4 + i) * 1024);
            glds16(Bg[i] + k0, ldsB + (wv * 4 + i) * 1024);
        }
        __syncthreads();
        #pragma unroll
        for (int kk = 0; kk < 2; ++kk) {
            bf16x8 af[4], bfr[4];
            #pragma unroll
            for (int i = 0; i < 4; ++i) {
                int r = wrow + i * 16 + (lane & 15);
                int c = (lane >> 4) + kk * 4;
                af[i]  = *(const bf16x8*)(ldsA + r * 128 + ((c ^ (r & 7)) * 16));
                int r2 = wcol + i * 16 + (lane & 15);
                bfr[i] = *(const bf16x8*)(ldsB + r2 * 128 + ((c ^ (r2 & 7)) * 16));
            }
            #pragma unroll
            for (int i = 0; i < 4; ++i)
                #pragma unroll
                for (int j = 0; j < 4; ++j)
                    acc[i][j] = __builtin_amdgcn_mfma_f32_16x16x32_bf16(af[i], bfr[j], acc[i][j], 0, 0, 0);
        }
        __syncthreads();
    }

    int colg[4]; float bv[4];
    #pragma unroll
    for (int j = 0; j < 4; ++j) {
        colg[j] = n0 + wcol + j * 16 + (lane & 15);
        bv[j]   = bias[colg[j]];
    }
    #pragma unroll
    for (int i = 0; i < 4; ++i) {
        #pragma unroll
        for (int r = 0; r < 4; ++r) {
            int rowg = m0 + wrow + i * 16 + ((lane >> 4) << 2) + r;
            int tok = (MODE == 1) ? tok_of_winrow(rowg) : rowg;
            #pragma unroll
            for (int j = 0; j < 4; ++j) {
                float v = acc[i][j][r] + bv[j];
                if (MODE == 0) {
                    ((ushort*)Cout)[(size_t)rowg * Nout + colg[j]] = f2b(v);
                } else if (MODE == 1) {
                    v += ((const float*)resid)[(size_t)tok * C_ + colg[j]];
                    ((float*)Cout)[(size_t)tok * C_ + colg[j]] = v;
                } else if (MODE == 2) {
                    ((ushort*)Cout)[(size_t)rowg * Nout + colg[j]] = f2b(gelu_exact(v));
                } else {
                    v += ((const float*)resid)[(size_t)rowg * Nout + colg[j]];
                    ((float*)Cout)[(size_t)rowg * Nout + colg[j]] = v;
                }
            }
        }
    }
}

// ---------------- MFMA windowed attention: 1 wave per (window, head) --------
// N=98 padded to 112 M/N-tiles (7x16), PV K-dim padded to 128.
// S = mfma(Qfrag, Kfrag) with frags loaded direct from global (A-frag layout).
// Full softmax in registers (C-layout), P -> bf16 via LDS relayout, V staged
// transposed in LDS so PV B-frags are contiguous 16B reads.
__global__ __launch_bounds__(64)
void attn_mfma(const ushort* __restrict__ qkv, const float* __restrict__ biasbuf,
               const float* __restrict__ mask, ushort* __restrict__ attn_out) {
    __shared__ __align__(16) ushort Vt[32][136];   // [d][j] transposed V
    __shared__ __align__(16) ushort Pl[16][136];   // current 16-row P block
    const int wid  = blockIdx.x >> 3;
    const int hh   = blockIdx.x & 7;
    const int lane = threadIdx.x;
    const int lrow = lane & 15, lgrp = lane >> 4;
    const float scale = 0.17677669529663687f;      // 1/sqrt(32)

    const ushort* base = qkv + (size_t)wid * N_ * 768 + hh * 32;
    const float* mbase = mask + (size_t)(wid & 255) * (N_ * N_);
    const float* bbase = biasbuf + (size_t)hh * (N_ * N_);

    // zero LDS (padding columns must be 0 to avoid NaN from pad*garbage)
    {
        uint4 z = {0, 0, 0, 0};
        uint4* v4 = (uint4*)&Vt[0][0];
        for (int i = lane; i < 32 * 136 / 8; i += 64) v4[i] = z;
        uint4* p4 = (uint4*)&Pl[0][0];
        for (int i = lane; i < 16 * 136 / 8; i += 64) p4[i] = z;
    }
    __syncthreads();

    // stage V transposed: Vt[d][j] = V[j][d]
    for (int idx = lane; idx < N_ * 4; idx += 64) {
        int j = idx >> 2, dg = idx & 3;
        uint4 v = *(const uint4*)(base + (size_t)j * 768 + 512 + dg * 8);
        const ushort* pv = (const ushort*)&v;
        #pragma unroll
        for (int t = 0; t < 8; ++t) Vt[dg * 8 + t][j] = pv[t];
    }

    // K fragments direct from global (A-frag layout: row=lane&15, k=(lane>>4)*8+t)
    bf16x8 kf[7];
    #pragma unroll
    for (int nj = 0; nj < 7; ++nj) {
        int j = nj * 16 + lrow;
        kf[nj] = *(const bf16x8*)(base + (size_t)j * 768 + 256 + lgrp * 8);
    }
    __syncthreads();

    // V fragments from Vt (B-frag: lane holds V[kt*32+lgrp*8+t][dt*16+lrow])
    bf16x8 vf[2][4];
    #pragma unroll
    for (int dt = 0; dt < 2; ++dt)
        #pragma unroll
        for (int kt = 0; kt < 4; ++kt)
            vf[dt][kt] = *(const bf16x8*)(&Vt[dt * 16 + lrow][kt * 32 + lgrp * 8]);

    for (int mi = 0; mi < 7; ++mi) {
        const int ibase = mi * 16;
        bf16x8 qf = *(const bf16x8*)(base + (size_t)(ibase + lrow) * 768 + lgrp * 8);

        f32x4 s[7];
        #pragma unroll
        for (int nj = 0; nj < 7; ++nj) {
            f32x4 z = {0.f, 0.f, 0.f, 0.f};
            s[nj] = __builtin_amdgcn_mfma_f32_16x16x32_bf16(qf, kf[nj], z, 0, 0, 0);
        }

        // scale + bias + mask in C-layout: row = ibase+lgrp*4+r, col = nj*16+lrow
        float sv[7][4];
        #pragma unroll
        for (int nj = 0; nj < 7; ++nj) {
            int j = nj * 16 + lrow;
            #pragma unroll
            for (int r = 0; r < 4; ++r) {
                int i = ibase + lgrp * 4 + r;
                if (j < N_ && i < N_)
                    sv[nj][r] = s[nj][r] * scale + bbase[i * N_ + j] + mbase[i * N_ + j];
                else
                    sv[nj][r] = -1e30f;
            }
        }

        // full softmax: reduce over nj (regs) then 16 lanes of the column group
        float mx[4], sum[4], rinv[4];
        #pragma unroll
        for (int r = 0; r < 4; ++r) {
            float m = sv[0][r];
            #pragma unroll
            for (int nj = 1; nj < 7; ++nj) m = fmaxf(m, sv[nj][r]);
            #pragma unroll
            for (int o = 1; o < 16; o <<= 1) m = fmaxf(m, __shfl_xor(m, o));
            mx[r] = m;
        }
        #pragma unroll
        for (int r = 0; r < 4; ++r) {
            float acc = 0.f;
            #pragma unroll
            for (int nj = 0; nj < 7; ++nj) {
                float p = __expf(sv[nj][r] - mx[r]);
                sv[nj][r] = p;
                acc += p;
            }
            #pragma unroll
            for (int o = 1; o < 16; o <<= 1) acc += __shfl_xor(acc, o);
            sum[r] = acc;
            rinv[r] = 1.f / acc;
        }

        __syncthreads();   // previous PV reads done before overwriting Pl
        #pragma unroll
        for (int nj = 0; nj < 7; ++nj)
            #pragma unroll
            for (int r = 0; r < 4; ++r)
                Pl[lgrp * 4 + r][nj * 16 + lrow] = f2b(sv[nj][r] * rinv[r]);
        __syncthreads();

        // PV: O[i][d] = sum_j P[i][j] V[j][d]
        f32x4 o0 = {0.f, 0.f, 0.f, 0.f}, o1 = {0.f, 0.f, 0.f, 0.f};
        #pragma unroll
        for (int kt = 0; kt < 4; ++kt) {
            bf16x8 pf = *(const bf16x8*)(&Pl[lrow][kt * 32 + lgrp * 8]);
            o0 = __builtin_amdgcn_mfma_f32_16x16x32_bf16(pf, vf[0][kt], o0, 0, 0, 0);
            o1 = __builtin_amdgcn_mfma_f32_16x16x32_bf16(pf, vf[1][kt], o1, 0, 0, 0);
        }

        #pragma unroll
        for (int r = 0; r < 4; ++r) {
            int i = ibase + lgrp * 4 + r;
            if (i < N_) {
                size_t rb = ((size_t)(wid * N_ + i)) * C_ + hh * 32;
                attn_out[rb + lrow]      = f2b(o0[r]);
                attn_out[rb + 16 + lrow] = f2b(o1[r]);
            }
        }
    }
}

// ---------------------------------------------------------------------------
extern "C" void kernel_launch(void* const* d_in, const int* in_sizes, int n_in,
                              void* d_out, int out_size, void* d_ws, size_t ws_size,
                              hipStream_t stream) {
    const float* x      = (const float*)d_in[0];
    const float* qkv_w  = (const float*)d_in[1];
    const float* qkv_b  = (const float*)d_in[2];
    const float* proj_w = (const float*)d_in[3];
    const float* proj_b = (const float*)d_in[4];
    const float* rpb    = (const float*)d_in[5];
    const float* ln1_g  = (const float*)d_in[6];
    const float* ln1_b  = (const float*)d_in[7];
    const float* ln2_g  = (const float*)d_in[8];
    const float* ln2_b  = (const float*)d_in[9];
    const float* fc1_w  = (const float*)d_in[10];
    const float* fc1_b  = (const float*)d_in[11];
    const float* fc2_w  = (const float*)d_in[12];
    const float* fc2_b  = (const float*)d_in[13];
    const int*   rel_idx= (const int*)d_in[14];
    const float* mask   = (const float*)d_in[15];
    float* out = (float*)d_out;

    char* ws = (char*)d_ws;
    ushort* regionA = (ushort*)ws;                                   // qkv/hidden bf16
    ushort* regionB = (ushort*)(ws + (size_t)TOK * HID * 2);         // win/attn_out/h2 bf16
    ushort* wq  = (ushort*)(ws + (size_t)TOK * HID * 2 + (size_t)TOK * C_ * 2);
    ushort* wp  = wq + 768 * 256;
    ushort* w1  = wp + 256 * 256;
    ushort* w2  = w1 + HID * 256;
    float* biasbuf = (float*)(w2 + 256 * HID);

    // K0: rel-pos bias gather + weight converts
    bias_kernel<<<(NH_ * N_ * N_ + 255) / 256, 256, 0, stream>>>(rel_idx, rpb, biasbuf);
    f2b_kernel<<<(768 * 256 / 4 + 255) / 256, 256, 0, stream>>>(qkv_w, wq, 768 * 256);
    f2b_kernel<<<(256 * 256 / 4 + 255) / 256, 256, 0, stream>>>(proj_w, wp, 256 * 256);
    f2b_kernel<<<(HID * 256 / 4 + 255) / 256, 256, 0, stream>>>(fc1_w, w1, HID * 256);
    f2b_kernel<<<(256 * HID / 4 + 255) / 256, 256, 0, stream>>>(fc2_w, w2, 256 * HID);

    // K1: LN1 + shift + window partition -> regionB bf16
    ln_kernel<true><<<TOK / 4, 256, 0, stream>>>(x, ln1_g, ln1_b, regionB, TOK);

    // K2: QKV GEMM -> regionA bf16 (50176 x 768)
    {
        dim3 g(TOK / 128, 768 / 128);
        gemm_bf16<0><<<g, 256, 0, stream>>>(regionB, wq, qkv_b, regionA, nullptr, TOK, 256, 768);
    }

    // K3: MFMA windowed attention -> regionB bf16
    attn_mfma<<<NWIN_TOT * NH_, 64, 0, stream>>>(regionA, biasbuf, mask, regionB);

    // K4: proj GEMM + window reverse + unshift + residual(x) -> out fp32
    {
        dim3 g(TOK / 128, 256 / 128);
        gemm_bf16<1><<<g, 256, 0, stream>>>(regionB, wp, proj_b, out, x, TOK, 256, 256);
    }

    // K5: LN2 -> regionB bf16
    ln_kernel<false><<<TOK / 4, 256, 0, stream>>>(out, ln2_g, ln2_b, regionB, TOK);

    // K6: fc1 + GELU -> regionA bf16 (50176 x 1024)
    {
        dim3 g(TOK / 128, HID / 128);
        gemm_bf16<2><<<g, 256, 0, stream>>>(regionB, w1, fc1_b, regionA, nullptr, TOK, 256, HID);
    }

    // K7: fc2 + residual (in place on out)
    {
        dim3 g(TOK / 128, 256 / 128);
        gemm_bf16<3><<<g, 256, 0, stream>>>(regionA, w2, fc2_b, out, out, TOK, HID, 256);
    }
}